// Round 2
// baseline (306.239 us; speedup 1.0000x reference)
//
#include <hip/hip_runtime.h>
#include <hip/hip_cooperative_groups.h>

namespace cg = cooperative_groups;

#define WAVE 64
#define WPB 4                 // waves per block
#define THREADS (WPB * WAVE)

__global__ __launch_bounds__(THREADS, 4)
void fused_hml_kernel(const float* __restrict__ x, const int* __restrict__ targets,
                      const float* __restrict__ w, int N, int D, int C,
                      int* __restrict__ cnt, float* __restrict__ S,
                      float* __restrict__ partials, float* __restrict__ out,
                      int nchunk) {
    cg::grid_group grid = cg::this_grid();
    const int tid = threadIdx.x;
    const int gid = blockIdx.x * THREADS + tid;
    const int nthreads = gridDim.x * THREADS;
    const int ncol4 = D >> 2;   // float4 columns

    // ---- Phase 0: zero cnt and S (replaces two hipMemsetAsync dispatches)
    for (int i = gid; i < C; i += nthreads) cnt[i] = 0;
    for (int i = gid; i < D; i += nthreads) S[i] = 0.f;

    grid.sync();

    // ---- Phase 1: class histogram + S[d] = sum_i w[targets[i]][d]
    if (gid < N) atomicAdd(&cnt[targets[gid]], 1);

    int total_s = ncol4 * nchunk;          // one thread per (float4-col, row-chunk)
    if (gid < total_s) {
        int d4    = gid % ncol4;           // consecutive gid -> consecutive d4 (coalesced)
        int chunk = gid / ncol4;           // wave-uniform -> targets loads are scalar
        int rows_per = (N + nchunk - 1) / nchunk;
        int r0 = chunk * rows_per;
        int r1 = min(r0 + rows_per, N);
        float ax = 0.f, ay = 0.f, az = 0.f, aw = 0.f;
        for (int i = r0; i < r1; ++i) {
            int t = targets[i];
            float4 v = ((const float4*)(w + (size_t)t * D))[d4];
            ax += v.x; ay += v.y; az += v.z; aw += v.w;
        }
        float* Sd = S + 4 * d4;
        atomicAdd(Sd + 0, ax);
        atomicAdd(Sd + 1, ay);
        atomicAdd(Sd + 2, az);
        atomicAdd(Sd + 3, aw);
    }

    grid.sync();

    // ---- Phase 2: per-row  dw = x_i.w[t_i],  ds = x_i.S
    //      term_i = 1 - dw + (ds - c_i*dw)/(N - c_i)
    __shared__ float sm[WPB];
    const int wave = tid >> 6, lane = tid & 63;
    const int row  = blockIdx.x * WPB + wave;
    float term = 0.f;
    if (row < N) {
        int t = targets[row];
        const float4* xr = (const float4*)(x + (size_t)row * D);
        const float4* wr = (const float4*)(w + (size_t)t * D);
        const float4* Sr = (const float4*)S;
        float dw = 0.f, ds = 0.f;
        for (int k = lane; k < ncol4; k += WAVE) {
            float4 a = xr[k], b = wr[k], s = Sr[k];
            dw += a.x*b.x + a.y*b.y + a.z*b.z + a.w*b.w;
            ds += a.x*s.x + a.y*s.y + a.z*s.z + a.w*s.w;
        }
        #pragma unroll
        for (int off = 32; off; off >>= 1) {
            dw += __shfl_down(dw, off);
            ds += __shfl_down(ds, off);
        }
        if (lane == 0) {
            float c = (float)cnt[t];
            term = 1.f - dw + (ds - c * dw) / ((float)N - c);
        }
    }
    if (lane == 0) sm[wave] = term;
    __syncthreads();
    if (tid == 0) {
        float p = 0.f;
        #pragma unroll
        for (int i = 0; i < WPB; ++i) p += sm[i];
        partials[blockIdx.x] = p;
    }

    grid.sync();

    // ---- Phase 3: block 0 reduces partials in double, writes mean
    if (blockIdx.x == 0) {
        int nb = gridDim.x;
        double acc = 0.0;
        for (int i = tid; i < nb; i += THREADS) acc += (double)partials[i];
        #pragma unroll
        for (int off = 32; off; off >>= 1) acc += __shfl_down(acc, off);
        __shared__ double dm[WPB];
        if (lane == 0) dm[wave] = acc;
        __syncthreads();
        if (tid == 0) {
            double s = 0.0;
            #pragma unroll
            for (int i = 0; i < WPB; ++i) s += dm[i];
            out[0] = (float)(s / (double)N);
        }
    }
}

extern "C" void kernel_launch(void* const* d_in, const int* in_sizes, int n_in,
                              void* d_out, int out_size, void* d_ws, size_t ws_size,
                              hipStream_t stream) {
    const float* x       = (const float*)d_in[0];
    const int*   targets = (const int*)d_in[1];
    const float* w       = (const float*)d_in[2];

    int N = in_sizes[1];
    int D = in_sizes[0] / N;
    int C = in_sizes[2] / D;

    char* wsb = (char*)d_ws;
    size_t cnt_bytes = ((size_t)C * sizeof(int) + 255) & ~(size_t)255;
    size_t s_bytes   = ((size_t)D * sizeof(float) + 255) & ~(size_t)255;
    int*   cnt      = (int*)wsb;
    float* S        = (float*)(wsb + cnt_bytes);
    float* partials = (float*)(wsb + cnt_bytes + s_bytes);
    float* out      = (float*)d_out;

    int blocks = (N + WPB - 1) / WPB;     // 1024 for N=4096 -> 4 blocks/CU, co-resident
    int nchunk = 32;                      // row-chunks for the S gather-sum

    void* args[] = {
        (void*)&x, (void*)&targets, (void*)&w,
        (void*)&N, (void*)&D, (void*)&C,
        (void*)&cnt, (void*)&S, (void*)&partials, (void*)&out,
        (void*)&nchunk
    };
    hipLaunchCooperativeKernel((void*)fused_hml_kernel, dim3(blocks), dim3(THREADS),
                               args, 0, stream);
}

// Round 3
// 41.577 us; speedup vs baseline: 7.3656x; 7.3656x over previous
//
#include <hip/hip_runtime.h>

#define WAVE 64
#define K2_WAVES 8
#define K2_THREADS (K2_WAVES * WAVE)

// K1: S_part[chunk][d] = sum_{i in chunk} w[targets[i]][d]
// Plain stores (no atomics, no zero-init). Also resets the completion flag.
__global__ __launch_bounds__(256)
void sgather_kernel(const float* __restrict__ w, const int* __restrict__ targets,
                    int N, int D, int nchunk, float* __restrict__ S_part,
                    int* __restrict__ flag) {
    if (blockIdx.x == 0 && threadIdx.x == 0) *flag = 0;
    const int chunk = blockIdx.x;
    const int rows_per = (N + nchunk - 1) / nchunk;
    const int r0 = chunk * rows_per;
    const int r1 = min(r0 + rows_per, N);
    const int ncol4 = D >> 2;
    for (int d4 = threadIdx.x; d4 < ncol4; d4 += blockDim.x) {
        float ax = 0.f, ay = 0.f, az = 0.f, aw = 0.f;
        #pragma unroll 8
        for (int i = r0; i < r1; ++i) {
            int t = targets[i];
            float4 v = ((const float4*)(w + (size_t)t * D))[d4];
            ax += v.x; ay += v.y; az += v.z; aw += v.w;
        }
        float4 o = make_float4(ax, ay, az, aw);
        ((float4*)(S_part + (size_t)chunk * D))[d4] = o;
    }
}

// K2: per-row terms + block partials + last-block finalize.
//   dw = x_i . w[t_i],  ds = x_i . S,  c_i = #{j: t_j == t_i}
//   term_i = 1 - dw + (ds - c_i*dw)/(N - c_i)
__global__ __launch_bounds__(K2_THREADS)
void row_kernel(const float* __restrict__ x, const int* __restrict__ targets,
                const float* __restrict__ w, const float* __restrict__ S_part,
                int N, int D, int nchunk,
                float* __restrict__ partials, int* __restrict__ flag,
                float* __restrict__ out) {
    __shared__ float S_lds[4096];          // up to D=4096 floats (D=1024 -> 4KB used)
    __shared__ float sm[K2_WAVES];
    __shared__ double dm[K2_WAVES];
    __shared__ int s_old;
    const int tid = threadIdx.x;
    const int ncol4 = D >> 2;

    // (a) reduce S_part -> S_lds (each thread owns float4 columns)
    for (int d4 = tid; d4 < ncol4; d4 += K2_THREADS) {
        float ax = 0.f, ay = 0.f, az = 0.f, aw = 0.f;
        #pragma unroll 8
        for (int c2 = 0; c2 < nchunk; ++c2) {
            float4 v = ((const float4*)(S_part + (size_t)c2 * D))[d4];
            ax += v.x; ay += v.y; az += v.z; aw += v.w;
        }
        ((float4*)S_lds)[d4] = make_float4(ax, ay, az, aw);
    }

    const int wave = tid >> 6, lane = tid & 63;
    const int row = blockIdx.x * K2_WAVES + wave;

    // (b) inline class count for this row (no histogram kernel, no memset)
    int t = 0, c = 0;
    if (row < N) {
        t = targets[row];
        #pragma unroll 8
        for (int j = lane; j < N; j += WAVE) c += (targets[j] == t) ? 1 : 0;
    }

    __syncthreads();   // S_lds ready

    // (c) dual dot products
    float term = 0.f;
    if (row < N) {
        const float4* xr = (const float4*)(x + (size_t)row * D);
        const float4* wr = (const float4*)(w + (size_t)t * D);
        const float4* Sr = (const float4*)S_lds;
        float dw = 0.f, ds = 0.f;
        #pragma unroll 2
        for (int k = lane; k < ncol4; k += WAVE) {
            float4 a = xr[k], b = wr[k], s = Sr[k];
            dw += a.x*b.x + a.y*b.y + a.z*b.z + a.w*b.w;
            ds += a.x*s.x + a.y*s.y + a.z*s.z + a.w*s.w;
        }
        #pragma unroll
        for (int off = 32; off; off >>= 1) {
            dw += __shfl_down(dw, off);
            ds += __shfl_down(ds, off);
            c  += __shfl_down(c,  off);
        }
        if (lane == 0) {
            float cf = (float)c;
            term = 1.f - dw + (ds - cf * dw) / ((float)N - cf);
        }
    }
    if (lane == 0) sm[wave] = term;
    __syncthreads();

    // (d) block partial + decoupled last-block finalize
    if (tid == 0) {
        float p = 0.f;
        #pragma unroll
        for (int i = 0; i < K2_WAVES; ++i) p += sm[i];
        partials[blockIdx.x] = p;
        __threadfence();                   // release partials before flag bump
        s_old = atomicAdd(flag, 1);
    }
    __syncthreads();
    if (s_old == (int)gridDim.x - 1) {
        __threadfence();                   // acquire all blocks' partials
        double acc = 0.0;
        for (int i = tid; i < (int)gridDim.x; i += K2_THREADS) acc += (double)partials[i];
        #pragma unroll
        for (int off = 32; off; off >>= 1) acc += __shfl_down(acc, off);
        if (lane == 0) dm[wave] = acc;
        __syncthreads();
        if (tid == 0) {
            double s2 = 0.0;
            #pragma unroll
            for (int i = 0; i < K2_WAVES; ++i) s2 += dm[i];
            out[0] = (float)(s2 / (double)N);
        }
    }
}

extern "C" void kernel_launch(void* const* d_in, const int* in_sizes, int n_in,
                              void* d_out, int out_size, void* d_ws, size_t ws_size,
                              hipStream_t stream) {
    const float* x       = (const float*)d_in[0];
    const int*   targets = (const int*)d_in[1];
    const float* w       = (const float*)d_in[2];

    int N = in_sizes[1];
    int D = in_sizes[0] / N;

    const int nchunk = 32;
    int nblocks = (N + K2_WAVES - 1) / K2_WAVES;   // 512 for N=4096

    char* wsb = (char*)d_ws;
    size_t sp_bytes = ((size_t)nchunk * D * sizeof(float) + 255) & ~(size_t)255;
    size_t p_bytes  = ((size_t)nblocks * sizeof(float) + 255) & ~(size_t)255;
    float* S_part   = (float*)wsb;
    float* partials = (float*)(wsb + sp_bytes);
    int*   flag     = (int*)(wsb + sp_bytes + p_bytes);

    sgather_kernel<<<nchunk, 256, 0, stream>>>(w, targets, N, D, nchunk, S_part, flag);
    row_kernel<<<nblocks, K2_THREADS, 0, stream>>>(x, targets, w, S_part, N, D, nchunk,
                                                   partials, flag, (float*)d_out);
}

// Round 4
// 38.396 us; speedup vs baseline: 7.9758x; 1.0828x over previous
//
#include <hip/hip_runtime.h>

#define WAVE 64
#define NCHUNK 64
#define K2_WAVES 8
#define K2_THREADS (K2_WAVES * WAVE)

// K1: S_part[chunk][d] = sum_{i in chunk} w[targets[i]][d]
// Targets staged in LDS first so every w-row gather address is independent
// (no dependent load chain -> full MLP). Plain stores, no zero-init needed.
__global__ __launch_bounds__(256)
void sgather_kernel(const float* __restrict__ w, const int* __restrict__ targets,
                    int N, int D, float* __restrict__ S_part,
                    int* __restrict__ flag) {
    if (blockIdx.x == 0 && threadIdx.x == 0) *flag = 0;
    __shared__ int t_lds[512];
    const int chunk = blockIdx.x;
    const int rows_per = (N + gridDim.x - 1) / gridDim.x;   // 64
    const int r0 = chunk * rows_per;
    const int r1 = min(r0 + rows_per, N);
    const int nrows = min(r1 - r0, 512);
    for (int i = threadIdx.x; i < nrows; i += blockDim.x)
        t_lds[i] = targets[r0 + i];
    __syncthreads();
    const int ncol4 = D >> 2;
    for (int d4 = threadIdx.x; d4 < ncol4; d4 += blockDim.x) {
        float ax = 0.f, ay = 0.f, az = 0.f, aw = 0.f;
        #pragma unroll 8
        for (int i = 0; i < nrows; ++i) {
            float4 v = ((const float4*)(w + (size_t)t_lds[i] * D))[d4];
            ax += v.x; ay += v.y; az += v.z; aw += v.w;
        }
        ((float4*)(S_part + (size_t)chunk * D))[d4] = make_float4(ax, ay, az, aw);
    }
}

// K2: per-row terms + block partials + last-block finalize.
//   dw = x_i . w[t_i],  ds = x_i . S,  c_i = #{j: t_j == t_i}
//   term_i = 1 - dw + (ds - c_i*dw)/(N - c_i)
__global__ __launch_bounds__(K2_THREADS)
void row_kernel(const float* __restrict__ x, const int* __restrict__ targets,
                const float* __restrict__ w, const float* __restrict__ S_part,
                int N, int D,
                float* __restrict__ partials, int* __restrict__ flag,
                float* __restrict__ out) {
    __shared__ float S_lds[4096];
    __shared__ float sm[K2_WAVES];
    __shared__ double dm[K2_WAVES];
    __shared__ int s_old;
    const int tid = threadIdx.x;
    const int ncol4 = D >> 2;

    // (a) reduce S_part -> S_lds; chunk addresses independent -> full MLP
    for (int d4 = tid; d4 < ncol4; d4 += K2_THREADS) {
        float ax = 0.f, ay = 0.f, az = 0.f, aw = 0.f;
        #pragma unroll 8
        for (int c2 = 0; c2 < NCHUNK; ++c2) {
            float4 v = ((const float4*)(S_part + (size_t)c2 * D))[d4];
            ax += v.x; ay += v.y; az += v.z; aw += v.w;
        }
        ((float4*)S_lds)[d4] = make_float4(ax, ay, az, aw);
    }

    const int wave = tid >> 6, lane = tid & 63;
    const int row = blockIdx.x * K2_WAVES + wave;

    // (b) inline class count for this row (targets is L1/L2-resident, 16 KB)
    int t = 0, c = 0;
    if (row < N) {
        t = targets[row];
        #pragma unroll 8
        for (int j = lane; j < N; j += WAVE) c += (targets[j] == t) ? 1 : 0;
    }

    __syncthreads();   // S_lds ready

    // (c) dual dot products
    float term = 0.f;
    if (row < N) {
        const float4* xr = (const float4*)(x + (size_t)row * D);
        const float4* wr = (const float4*)(w + (size_t)t * D);
        const float4* Sr = (const float4*)S_lds;
        float dw = 0.f, ds = 0.f;
        #pragma unroll 4
        for (int k = lane; k < ncol4; k += WAVE) {
            float4 a = xr[k], b = wr[k], s = Sr[k];
            dw += a.x*b.x + a.y*b.y + a.z*b.z + a.w*b.w;
            ds += a.x*s.x + a.y*s.y + a.z*s.z + a.w*s.w;
        }
        #pragma unroll
        for (int off = 32; off; off >>= 1) {
            dw += __shfl_down(dw, off);
            ds += __shfl_down(ds, off);
            c  += __shfl_down(c,  off);
        }
        if (lane == 0) {
            float cf = (float)c;
            term = 1.f - dw + (ds - cf * dw) / ((float)N - cf);
        }
    }
    if (lane == 0) sm[wave] = term;
    __syncthreads();

    // (d) block partial + decoupled last-block finalize
    if (tid == 0) {
        float p = 0.f;
        #pragma unroll
        for (int i = 0; i < K2_WAVES; ++i) p += sm[i];
        partials[blockIdx.x] = p;
        __threadfence();
        s_old = atomicAdd(flag, 1);
    }
    __syncthreads();
    if (s_old == (int)gridDim.x - 1) {
        __threadfence();
        double acc = 0.0;
        for (int i = tid; i < (int)gridDim.x; i += K2_THREADS) acc += (double)partials[i];
        #pragma unroll
        for (int off = 32; off; off >>= 1) acc += __shfl_down(acc, off);
        if (lane == 0) dm[wave] = acc;
        __syncthreads();
        if (tid == 0) {
            double s2 = 0.0;
            #pragma unroll
            for (int i = 0; i < K2_WAVES; ++i) s2 += dm[i];
            out[0] = (float)(s2 / (double)N);
        }
    }
}

extern "C" void kernel_launch(void* const* d_in, const int* in_sizes, int n_in,
                              void* d_out, int out_size, void* d_ws, size_t ws_size,
                              hipStream_t stream) {
    const float* x       = (const float*)d_in[0];
    const int*   targets = (const int*)d_in[1];
    const float* w       = (const float*)d_in[2];

    int N = in_sizes[1];
    int D = in_sizes[0] / N;

    int nblocks = (N + K2_WAVES - 1) / K2_WAVES;   // 512 for N=4096

    char* wsb = (char*)d_ws;
    size_t sp_bytes = ((size_t)NCHUNK * D * sizeof(float) + 255) & ~(size_t)255;
    size_t p_bytes  = ((size_t)nblocks * sizeof(float) + 255) & ~(size_t)255;
    float* S_part   = (float*)wsb;
    float* partials = (float*)(wsb + sp_bytes);
    int*   flag     = (int*)(wsb + sp_bytes + p_bytes);

    sgather_kernel<<<NCHUNK, 256, 0, stream>>>(w, targets, N, D, S_part, flag);
    row_kernel<<<nblocks, K2_THREADS, 0, stream>>>(x, targets, w, S_part, N, D,
                                                   partials, flag, (float*)d_out);
}

// Round 5
// 36.819 us; speedup vs baseline: 8.3174x; 1.0428x over previous
//
#include <hip/hip_runtime.h>

#define WAVE 64
#define NCHUNK 64
#define K2_WAVES 8
#define K2_THREADS (K2_WAVES * WAVE)

// K1: S_part[chunk][d] = sum_{i in chunk} w[targets[i]][d]
// Targets staged in LDS (independent gather addresses -> full MLP).
// Plain stores, no zero-init. Also resets K2's completion flag.
__global__ __launch_bounds__(256)
void sgather_kernel(const float* __restrict__ w, const int* __restrict__ targets,
                    int N, int D, float* __restrict__ S_part,
                    int* __restrict__ flagB) {
    if (blockIdx.x == 0 && threadIdx.x == 0) *flagB = 0;
    __shared__ int t_lds[512];
    const int chunk = blockIdx.x;
    const int rows_per = (N + NCHUNK - 1) / NCHUNK;     // 64 for N=4096
    const int r0 = chunk * rows_per;
    const int nrows = min(min(rows_per, N - r0), 512);
    for (int i = threadIdx.x; i < nrows; i += blockDim.x)
        t_lds[i] = targets[r0 + i];
    __syncthreads();
    const int ncol4 = D >> 2;
    for (int d4 = threadIdx.x; d4 < ncol4; d4 += blockDim.x) {
        float ax = 0.f, ay = 0.f, az = 0.f, aw = 0.f;
        #pragma unroll 8
        for (int i = 0; i < nrows; ++i) {
            float4 v = ((const float4*)(w + (size_t)t_lds[i] * D))[d4];
            ax += v.x; ay += v.y; az += v.z; aw += v.w;
        }
        ((float4*)(S_part + (size_t)chunk * D))[d4] = make_float4(ax, ay, az, aw);
    }
}

// K1b: S[d] = sum_chunk S_part[chunk][d]. One float4 column per thread,
// 64-thread blocks spread across CUs. Reads 256 KB once (vs 128 MB if K2
// re-reduced per block).
__global__ __launch_bounds__(64)
void sreduce_kernel(const float* __restrict__ S_part, int D, float* __restrict__ S) {
    const int d4 = blockIdx.x * 64 + threadIdx.x;
    const int ncol4 = D >> 2;
    if (d4 >= ncol4) return;
    float ax = 0.f, ay = 0.f, az = 0.f, aw = 0.f;
    #pragma unroll 8
    for (int c2 = 0; c2 < NCHUNK; ++c2) {
        float4 v = ((const float4*)(S_part + (size_t)c2 * D))[d4];
        ax += v.x; ay += v.y; az += v.z; aw += v.w;
    }
    ((float4*)S)[d4] = make_float4(ax, ay, az, aw);
}

// K2: per-row terms + block partials + last-block finalize.
//   dw = x_i . w[t_i],  ds = x_i . S,  c_i = #{j: t_j == t_i}
//   term_i = 1 - dw + (ds - c_i*dw)/(N - c_i)
// S read from global (4 KB, L1-broadcast). No LDS staging -> tiny LDS, 4 blk/CU.
__global__ __launch_bounds__(K2_THREADS)
void row_kernel(const float* __restrict__ x, const int* __restrict__ targets,
                const float* __restrict__ w, const float* __restrict__ S,
                int N, int D,
                float* __restrict__ partials, int* __restrict__ flagB,
                float* __restrict__ out) {
    __shared__ float sm[K2_WAVES];
    __shared__ double dm[K2_WAVES];
    __shared__ int s_old;
    const int tid = threadIdx.x;
    const int wave = tid >> 6, lane = tid & 63;
    const int row = blockIdx.x * K2_WAVES + wave;
    const int ncol4 = D >> 2;

    float term = 0.f;
    if (row < N) {
        const int t = targets[row];
        // inline class count (targets = 16 KB, L1-resident)
        int c = 0;
        #pragma unroll 8
        for (int j = lane; j < N; j += WAVE) c += (targets[j] == t) ? 1 : 0;

        const float4* xr = (const float4*)(x + (size_t)row * D);
        const float4* wr = (const float4*)(w + (size_t)t * D);
        const float4* Sr = (const float4*)S;
        float dw = 0.f, ds = 0.f;
        #pragma unroll 4
        for (int k = lane; k < ncol4; k += WAVE) {
            float4 a = xr[k], b = wr[k], s = Sr[k];
            dw += a.x*b.x + a.y*b.y + a.z*b.z + a.w*b.w;
            ds += a.x*s.x + a.y*s.y + a.z*s.z + a.w*s.w;
        }
        #pragma unroll
        for (int off = 32; off; off >>= 1) {
            dw += __shfl_down(dw, off);
            ds += __shfl_down(ds, off);
            c  += __shfl_down(c,  off);
        }
        if (lane == 0) {
            float cf = (float)c;
            term = 1.f - dw + (ds - cf * dw) / ((float)N - cf);
        }
    }
    if (lane == 0) sm[wave] = term;
    __syncthreads();

    if (tid == 0) {
        float p = 0.f;
        #pragma unroll
        for (int i = 0; i < K2_WAVES; ++i) p += sm[i];
        partials[blockIdx.x] = p;
        __threadfence();
        s_old = atomicAdd(flagB, 1);
    }
    __syncthreads();
    if (s_old == (int)gridDim.x - 1) {
        __threadfence();
        double acc = 0.0;
        for (int i = tid; i < (int)gridDim.x; i += K2_THREADS) acc += (double)partials[i];
        #pragma unroll
        for (int off = 32; off; off >>= 1) acc += __shfl_down(acc, off);
        if (lane == 0) dm[wave] = acc;
        __syncthreads();
        if (tid == 0) {
            double s2 = 0.0;
            #pragma unroll
            for (int i = 0; i < K2_WAVES; ++i) s2 += dm[i];
            out[0] = (float)(s2 / (double)N);
        }
    }
}

extern "C" void kernel_launch(void* const* d_in, const int* in_sizes, int n_in,
                              void* d_out, int out_size, void* d_ws, size_t ws_size,
                              hipStream_t stream) {
    const float* x       = (const float*)d_in[0];
    const int*   targets = (const int*)d_in[1];
    const float* w       = (const float*)d_in[2];

    int N = in_sizes[1];
    int D = in_sizes[0] / N;

    int nblocks = (N + K2_WAVES - 1) / K2_WAVES;   // 512 for N=4096
    int ncol4 = D >> 2;

    char* wsb = (char*)d_ws;
    size_t sp_bytes = ((size_t)NCHUNK * D * sizeof(float) + 255) & ~(size_t)255;
    size_t s_bytes  = ((size_t)D * sizeof(float) + 255) & ~(size_t)255;
    size_t p_bytes  = ((size_t)nblocks * sizeof(float) + 255) & ~(size_t)255;
    float* S_part   = (float*)wsb;
    float* S        = (float*)(wsb + sp_bytes);
    float* partials = (float*)(wsb + sp_bytes + s_bytes);
    int*   flagB    = (int*)(wsb + sp_bytes + s_bytes + p_bytes);

    sgather_kernel<<<NCHUNK, 256, 0, stream>>>(w, targets, N, D, S_part, flagB);
    sreduce_kernel<<<(ncol4 + 63) / 64, 64, 0, stream>>>(S_part, D, S);
    row_kernel<<<nblocks, K2_THREADS, 0, stream>>>(x, targets, w, S, N, D,
                                                   partials, flagB, (float*)d_out);
}